// Round 10
// baseline (115.926 us; speedup 1.0000x reference)
//
#include <hip/hip_runtime.h>
#include <math.h>

#define B_ 64
#define T_ 256
#define K_ 128

typedef const __attribute__((address_space(1))) void* gas1_t;
typedef __attribute__((address_space(3))) void* las3_t;
typedef float f32x4 __attribute__((ext_vector_type(4)));
typedef short bf16x8 __attribute__((ext_vector_type(8)));

static __device__ __forceinline__ unsigned int bf16rne(float x) {
    unsigned int u = __builtin_bit_cast(unsigned int, x);
    return (u + 0x7FFFu + ((u >> 16) & 1u)) >> 16;
}
static __device__ __forceinline__ unsigned int pkbf16(float a, float b) {
    return bf16rne(a) | (bf16rne(b) << 16);
}

// ---------------------------------------------------------------------------
// Bidirectional matvec chains (R7 skeleton, 4 waves/block, __syncthreads --
// the R9 "light barrier"+sched_barrier variant REGRESSED; do not reintroduce).
//   forward  (dir=0): v_H = prod_{t=H..1} D_t Texp  e_SOS          (H steps)
//   backward (dir=1): z = ey_{L-1}; z <- ey_t (.) Texp^T z, t=L-2..H;
//                     w = Texp^T z                                  (L-H steps)
//   out = c_f + c_b + log(v_H . w)   (combine kernel)
// Wave w owns rows [32w,32w+32): 8 MFMA/step (split-K 2+2). v exchanged via
// double-buffered LDS. NEW vs R7: ey for step t+1 is loaded into REGISTERS
// before step t's barrier (eybuf is chunk-immutable) -- its ds_read latency
// rides the same lgkm drain as the v-write instead of adding to the
// post-barrier critical path; the per-step if(eyp) branch is gone.
// ---------------------------------------------------------------------------
__global__ __launch_bounds__(256) void crf_chain_kernel(
    const float* __restrict__ y,
    const float* __restrict__ mask,
    const float* __restrict__ trans,
    float* __restrict__ vws,     // [B*2][128] end-state vectors (f32)
    float* __restrict__ cws)     // [B*2]      accumulated log-scales
{
    const int bd   = blockIdx.x;
    const int b    = bd >> 1;
    const int dir  = bd & 1;
    const int tid  = threadIdx.x;
    const int w    = tid >> 6;
    const int lane = tid & 63;
    const int q    = lane >> 4;
    const int ci   = lane & 15;

    __shared__ __align__(16) float eybuf[2][32 * K_];    // 2 x 16 KB y chunks
    __shared__ __align__(16) unsigned short vS[2][K_];   // v double buffer (bf16)
    __shared__ __align__(16) float wsumS[4];             // deferred renorm partials
    __shared__ int lenS[4];

    const float* yb = y + (size_t)b * (T_ * K_);

    // ---- sequence length first (backward staging needs L) ----
    {
        float mval = mask[b * T_ + tid];
        unsigned long long bal = __ballot(mval != 0.0f);
        if (lane == 0) lenS[w] = __popcll(bal);
    }
    __syncthreads();
    const int L = lenS[0] + lenS[1] + lenS[2] + lenS[3];   // in [128, 256]
    const int H = L >> 1;
    const int nch = dir ? ((L - H + 31) >> 5) : ((H + 31) >> 5);

    auto stage = [&](int row0, int buf) {                // 4 global_load_lds/wave
        const float* gp = yb + (size_t)row0 * K_;
        #pragma unroll
        for (int s4 = 0; s4 < 4; ++s4) {
            const int seg = 4 * w + s4;                  // 16 segments x 1 KB
            __builtin_amdgcn_global_load_lds(
                (gas1_t)(gp + seg * 256 + lane * 4),
                (las3_t)(&eybuf[buf][seg * 256]), 16, 0, 0);
        }
    };
    stage(dir ? (L - 32) : 0, 0);

    // ---- A-frags: A[m=ci][k=8q+j] for rows 32w+16mt+ci (R0-proven layout) ----
    // forward: A = Texp (row-major reads); backward: A = Texp^T (strided, once)
    bf16x8 A[2][4];
    if (!dir) {
        #pragma unroll
        for (int mt = 0; mt < 2; ++mt) {
            const float* tp = trans + (32 * w + 16 * mt + ci) * K_;
            #pragma unroll
            for (int kt = 0; kt < 4; ++kt) {
                f32x4 p = *(const f32x4*)(tp + 32 * kt + 8 * q);
                f32x4 r = *(const f32x4*)(tp + 32 * kt + 8 * q + 4);
                uint4 u = make_uint4(pkbf16(__expf(p.x), __expf(p.y)),
                                     pkbf16(__expf(p.z), __expf(p.w)),
                                     pkbf16(__expf(r.x), __expf(r.y)),
                                     pkbf16(__expf(r.z), __expf(r.w)));
                A[mt][kt] = __builtin_bit_cast(bf16x8, u);
            }
        }
    } else {
        #pragma unroll
        for (int mt = 0; mt < 2; ++mt) {
            const int rowm = 32 * w + 16 * mt + ci;
            #pragma unroll
            for (int kt = 0; kt < 4; ++kt) {
                const float* cp = trans + (size_t)(32 * kt + 8 * q) * K_ + rowm;
                float e0 = __expf(cp[0 * K_]), e1 = __expf(cp[1 * K_]);
                float e2 = __expf(cp[2 * K_]), e3 = __expf(cp[3 * K_]);
                float e4 = __expf(cp[4 * K_]), e5 = __expf(cp[5 * K_]);
                float e6 = __expf(cp[6 * K_]), e7 = __expf(cp[7 * K_]);
                uint4 u = make_uint4(pkbf16(e0, e1), pkbf16(e2, e3),
                                     pkbf16(e4, e5), pkbf16(e6, e7));
                A[mt][kt] = __builtin_bit_cast(bf16x8, u);
            }
        }
    }

    // ---- state init: forward = one-hot SOS (elem 2 -> word 1 low half) ----
    if (!dir) ((unsigned int*)&vS[0][0])[lane] = (lane == 1) ? 0x3F80u : 0u;

    float c_acc = 0.0f;
    int cur = 0;
    int tstep = 0;

    // One step. ey passed in registers (loaded LAST iteration, pre-barrier);
    // issues the NEXT step's ey loads (if nxt) into *ne0/*ne1 before the
    // barrier so their latency overlaps the v-write lgkm drain.
    auto stepv = [&](f32x4 ey0, f32x4 ey1, const float* nxt,
                     f32x4* ne0, f32x4* ne1) {
        const unsigned short* vp = vS[cur];
        bf16x8 Bf[4];
        #pragma unroll
        for (int kt = 0; kt < 4; ++kt)
            Bf[kt] = *(const bf16x8*)&vp[32 * kt + 8 * q];

        // split-K: two 2-deep chains per output tile, summed
        f32x4 a0 = {0.f, 0.f, 0.f, 0.f}, a0b = {0.f, 0.f, 0.f, 0.f};
        f32x4 a1 = {0.f, 0.f, 0.f, 0.f}, a1b = {0.f, 0.f, 0.f, 0.f};
        a0  = __builtin_amdgcn_mfma_f32_16x16x32_bf16(A[0][0], Bf[0], a0,  0, 0, 0);
        a1  = __builtin_amdgcn_mfma_f32_16x16x32_bf16(A[1][0], Bf[0], a1,  0, 0, 0);
        a0b = __builtin_amdgcn_mfma_f32_16x16x32_bf16(A[0][2], Bf[2], a0b, 0, 0, 0);
        a1b = __builtin_amdgcn_mfma_f32_16x16x32_bf16(A[1][2], Bf[2], a1b, 0, 0, 0);
        a0  = __builtin_amdgcn_mfma_f32_16x16x32_bf16(A[0][1], Bf[1], a0,  0, 0, 0);
        a1  = __builtin_amdgcn_mfma_f32_16x16x32_bf16(A[1][1], Bf[1], a1,  0, 0, 0);
        a0b = __builtin_amdgcn_mfma_f32_16x16x32_bf16(A[0][3], Bf[3], a0b, 0, 0, 0);
        a1b = __builtin_amdgcn_mfma_f32_16x16x32_bf16(A[1][3], Bf[3], a1b, 0, 0, 0);
        f32x4 w0 = (a0 + a0b) * ey0;
        f32x4 w1 = (a1 + a1b) * ey1;

        if (tstep && (tstep & 3) == 0) {     // consume partials from tstep-1
            f32x4 ws = *(const f32x4*)wsumS;
            float S = (ws.x + ws.y) + (ws.z + ws.w);
            float rinv = __builtin_amdgcn_rcpf(S);
            c_acc += __logf(S);
            w0 *= rinv; w1 *= rinv;
        }
        if ((tstep & 3) == 3) {              // publish partial sums
            f32x4 sv = w0 + w1;
            float sp = (sv.x + sv.y) + (sv.z + sv.w);
            sp += __shfl_xor(sp, 16);
            sp += __shfl_xor(sp, 32);
            if (lane == 0) wsumS[w] = sp;
        }
        if (ci == 0) {                       // 8 x 8B writes per wave
            uint2 d0 = make_uint2(pkbf16(w0.x, w0.y), pkbf16(w0.z, w0.w));
            uint2 d1 = make_uint2(pkbf16(w1.x, w1.y), pkbf16(w1.z, w1.w));
            *(uint2*)&vS[cur ^ 1][32 * w + 4 * q]      = d0;
            *(uint2*)&vS[cur ^ 1][32 * w + 16 + 4 * q] = d1;
        }
        if (nxt) {                           // prefetch next step's ey (regs)
            *ne0 = *(const f32x4*)(nxt + 32 * w + 4 * q);
            *ne1 = *(const f32x4*)(nxt + 32 * w + 4 * q + 16);
        }
        __syncthreads();
        cur ^= 1;
        ++tstep;
    };

    const int eyo = 32 * w + 4 * q;

    for (int c = 0; c < nch; ++c) {
        if (c + 1 < nch) {                   // prefetch next chunk
            stage(dir ? (L - 32 * (c + 2)) : (32 * (c + 1)), (c + 1) & 1);
            asm volatile("s_waitcnt vmcnt(4)" ::: "memory");   // chunk c's 4 done
        } else {
            asm volatile("s_waitcnt vmcnt(0)" ::: "memory");
        }
        __syncthreads();                     // all waves' DMA for chunk c visible
        float* bp = eybuf[c & 1];
        #pragma unroll
        for (int i = 0; i < 4; ++i) {        // pre-exp pass (4096 floats/256 thr)
            f32x4 v4 = *(const f32x4*)(bp + i * 1024 + tid * 4);
            v4.x = __expf(v4.x); v4.y = __expf(v4.y);
            v4.z = __expf(v4.z); v4.w = __expf(v4.w);
            *(f32x4*)(bp + i * 1024 + tid * 4) = v4;
        }
        __syncthreads();

        if (!dir) {                          // rows t = 32c + li, ascending
            const int ns = (H - 32 * c) < 32 ? (H - 32 * c) : 32;
            f32x4 e0 = *(const f32x4*)(bp + eyo);
            f32x4 e1 = *(const f32x4*)(bp + eyo + 16);
            for (int li = 0; li < ns; ++li) {
                const float* np = (li + 1 < ns) ? (bp + (li + 1) * K_) : nullptr;
                stepv(e0, e1, np, &e0, &e1);
            }
        } else {
            if (c == 0) {                    // init z = ey_{L-1} (row 31):
                float a0 = bp[31 * K_ + 2 * lane];     // all waves write the
                float a1 = bp[31 * K_ + 2 * lane + 1]; // same 64 words redundantly
                ((unsigned int*)&vS[0][0])[lane] = pkbf16(a0, a1);
                asm volatile("s_waitcnt lgkmcnt(0)" ::: "memory");
                __builtin_amdgcn_sched_barrier(0);
            }
            const int base = L - 32 * (c + 1);
            const int ls = (c == 0) ? 30 : 31;          // li=31 of c=0 was init
            int le = H - base; if (le < 0) le = 0;      // stop at t = H
            if (ls >= le) {
                f32x4 e0 = *(const f32x4*)(bp + ls * K_ + eyo);
                f32x4 e1 = *(const f32x4*)(bp + ls * K_ + eyo + 16);
                for (int li = ls; li >= le; --li) {
                    const float* np = (li - 1 >= le) ? (bp + (li - 1) * K_) : nullptr;
                    stepv(e0, e1, np, &e0, &e1);
                }
            }
        }
    }
    if (dir) {                               // final unscaled Texp^T application
        const f32x4 one = {1.f, 1.f, 1.f, 1.f};
        stepv(one, one, nullptr, nullptr, nullptr);
    }

    // ---- store end state (bf16 widened to f32) + log-scale ----
    if (tid < K_) {
        unsigned int hv = vS[cur][tid];
        vws[(size_t)bd * K_ + tid] = __builtin_bit_cast(float, hv << 16);
    }
    if (tid == 0) cws[bd] = c_acc;
}

// ---------------------------------------------------------------------------
// Combine: out[b] = c_f + c_b + log( v_H . w )
// ---------------------------------------------------------------------------
__global__ __launch_bounds__(128) void crf_comb_kernel(
    const float* __restrict__ vws,
    const float* __restrict__ cws,
    float* __restrict__ out)
{
    const int b   = blockIdx.x;
    const int tid = threadIdx.x;             // 0..127
    __shared__ float red2[2];

    float p = vws[(size_t)(2 * b) * K_ + tid] * vws[(size_t)(2 * b + 1) * K_ + tid];
    p += __shfl_xor(p, 1);  p += __shfl_xor(p, 2);
    p += __shfl_xor(p, 4);  p += __shfl_xor(p, 8);
    p += __shfl_xor(p, 16); p += __shfl_xor(p, 32);
    if ((tid & 63) == 0) red2[tid >> 6] = p;
    __syncthreads();
    if (tid == 0) out[b] = cws[2 * b] + cws[2 * b + 1] + __logf(red2[0] + red2[1]);
}

extern "C" void kernel_launch(void* const* d_in, const int* in_sizes, int n_in,
                              void* d_out, int out_size, void* d_ws, size_t ws_size,
                              hipStream_t stream) {
    const float* y     = (const float*)d_in[0];   // (B, T, K) fp32
    const float* mask  = (const float*)d_in[1];   // (B, T)    fp32 0/1
    const float* trans = (const float*)d_in[2];   // (K, K)    fp32
    float* out = (float*)d_out;                   // (B,)      fp32

    float* vws = (float*)d_ws;                              // 64 KB
    float* cws = (float*)((char*)d_ws + (size_t)B_ * 2 * K_ * sizeof(float));

    crf_chain_kernel<<<B_ * 2, 256, 0, stream>>>(y, mask, trans, vws, cws);
    crf_comb_kernel<<<B_, 128, 0, stream>>>(vws, cws, out);
}

// Round 11
// 111.147 us; speedup vs baseline: 1.0430x; 1.0430x over previous
//
#include <hip/hip_runtime.h>
#include <math.h>

#define B_ 64
#define T_ 256
#define K_ 128

typedef const __attribute__((address_space(1))) void* gas1_t;
typedef __attribute__((address_space(3))) void* las3_t;
typedef float f32x4 __attribute__((ext_vector_type(4)));
typedef short bf16x8 __attribute__((ext_vector_type(8)));

static __device__ __forceinline__ unsigned int bf16rne(float x) {
    unsigned int u = __builtin_bit_cast(unsigned int, x);
    return (u + 0x7FFFu + ((u >> 16) & 1u)) >> 16;
}
static __device__ __forceinline__ unsigned int pkbf16(float a, float b) {
    return bf16rne(a) | (bf16rne(b) << 16);
}

// ---------------------------------------------------------------------------
// Bidirectional matvec chains (half the serial depth of the R0 kernel, same
// proven per-step structure, and 1/64 the FLOPs of the R1-R6 matrix scheme).
//   forward  (dir=0): v_H = prod_{t=H..1} D_t Texp  e_SOS          (H steps)
//   backward (dir=1): z = ey_{L-1}; z <- ey_t (.) Texp^T z, t=L-2..H;
//                     w = Texp^T z                                  (L-H steps)
//   out = c_f + c_b + log(v_H . w)   (combine kernel)
// Per block: 4 waves, wave w owns rows [32w,32w+32): 2 mt x 4 kt = 8 MFMA per
// step; v round-trips through double-buffered LDS (16-lane broadcast reads);
// y staged in 16KB chunks via global_load_lds + pre-exp pass; renorm every 4
// steps via deferred partials (R0-verbatim).
//
// CONSOLIDATION NOTE (R11): this exact form measured 54.2 us (bench 111.2).
// Attempts that REGRESSED and must not be reintroduced:
//   - one-wave/no-barrier variant (R8: 136 us -- serialized LDS round-trip)
//   - raw lgkm-barrier + sched_barrier(0) fences (R9: 57.5 us)
//   - ey register-prefetch restructure (R10: 61.0 us)
//   - inline-asm v_cvt_pk_bf16_f32 pack (R3: NaN)
// The step is a latency chain the compiler schedules best from plain code.
// ---------------------------------------------------------------------------
__global__ __launch_bounds__(256) void crf_chain_kernel(
    const float* __restrict__ y,
    const float* __restrict__ mask,
    const float* __restrict__ trans,
    float* __restrict__ vws,     // [B*2][128] end-state vectors (f32)
    float* __restrict__ cws)     // [B*2]      accumulated log-scales
{
    const int bd   = blockIdx.x;
    const int b    = bd >> 1;
    const int dir  = bd & 1;
    const int tid  = threadIdx.x;
    const int w    = tid >> 6;
    const int lane = tid & 63;
    const int q    = lane >> 4;
    const int ci   = lane & 15;

    __shared__ __align__(16) float eybuf[2][32 * K_];    // 2 x 16 KB y chunks
    __shared__ __align__(16) unsigned short vS[2][K_];   // v double buffer (bf16)
    __shared__ __align__(16) float wsumS[4];             // deferred renorm partials
    __shared__ int lenS[4];

    const float* yb = y + (size_t)b * (T_ * K_);

    // ---- sequence length first (backward staging needs L) ----
    {
        float mval = mask[b * T_ + tid];
        unsigned long long bal = __ballot(mval != 0.0f);
        if (lane == 0) lenS[w] = __popcll(bal);
    }
    __syncthreads();
    const int L = lenS[0] + lenS[1] + lenS[2] + lenS[3];   // in [128, 256]
    const int H = L >> 1;
    const int nch = dir ? ((L - H + 31) >> 5) : ((H + 31) >> 5);

    auto stage = [&](int row0, int buf) {                // 4 global_load_lds/wave
        const float* gp = yb + (size_t)row0 * K_;
        #pragma unroll
        for (int s4 = 0; s4 < 4; ++s4) {
            const int seg = 4 * w + s4;                  // 16 segments x 1 KB
            __builtin_amdgcn_global_load_lds(
                (gas1_t)(gp + seg * 256 + lane * 4),
                (las3_t)(&eybuf[buf][seg * 256]), 16, 0, 0);
        }
    };
    stage(dir ? (L - 32) : 0, 0);

    // ---- A-frags: A[m=ci][k=8q+j] for rows 32w+16mt+ci (R0-proven layout) ----
    // forward: A = Texp (row-major reads); backward: A = Texp^T (strided, once)
    bf16x8 A[2][4];
    if (!dir) {
        #pragma unroll
        for (int mt = 0; mt < 2; ++mt) {
            const float* tp = trans + (32 * w + 16 * mt + ci) * K_;
            #pragma unroll
            for (int kt = 0; kt < 4; ++kt) {
                f32x4 p = *(const f32x4*)(tp + 32 * kt + 8 * q);
                f32x4 r = *(const f32x4*)(tp + 32 * kt + 8 * q + 4);
                uint4 u = make_uint4(pkbf16(__expf(p.x), __expf(p.y)),
                                     pkbf16(__expf(p.z), __expf(p.w)),
                                     pkbf16(__expf(r.x), __expf(r.y)),
                                     pkbf16(__expf(r.z), __expf(r.w)));
                A[mt][kt] = __builtin_bit_cast(bf16x8, u);
            }
        }
    } else {
        #pragma unroll
        for (int mt = 0; mt < 2; ++mt) {
            const int rowm = 32 * w + 16 * mt + ci;
            #pragma unroll
            for (int kt = 0; kt < 4; ++kt) {
                const float* cp = trans + (size_t)(32 * kt + 8 * q) * K_ + rowm;
                float e0 = __expf(cp[0 * K_]), e1 = __expf(cp[1 * K_]);
                float e2 = __expf(cp[2 * K_]), e3 = __expf(cp[3 * K_]);
                float e4 = __expf(cp[4 * K_]), e5 = __expf(cp[5 * K_]);
                float e6 = __expf(cp[6 * K_]), e7 = __expf(cp[7 * K_]);
                uint4 u = make_uint4(pkbf16(e0, e1), pkbf16(e2, e3),
                                     pkbf16(e4, e5), pkbf16(e6, e7));
                A[mt][kt] = __builtin_bit_cast(bf16x8, u);
            }
        }
    }

    // ---- state init: forward = one-hot SOS (elem 2 -> word 1 low half) ----
    if (!dir) ((unsigned int*)&vS[0][0])[lane] = (lane == 1) ? 0x3F80u : 0u;

    float c_acc = 0.0f;
    int cur = 0;
    int tstep = 0;

    auto step = [&](const float* eyp) {                  // R0-verbatim step
        const unsigned short* vp = vS[cur];
        bf16x8 Bf[4];
        #pragma unroll
        for (int kt = 0; kt < 4; ++kt)
            Bf[kt] = *(const bf16x8*)&vp[32 * kt + 8 * q];

        f32x4 ey0, ey1;
        if (eyp) {
            ey0 = *(const f32x4*)(eyp + 32 * w + 4 * q);
            ey1 = *(const f32x4*)(eyp + 32 * w + 4 * q + 16);
        } else {
            ey0 = (f32x4){1.f, 1.f, 1.f, 1.f};
            ey1 = ey0;
        }

        f32x4 a0 = {0.f, 0.f, 0.f, 0.f}, a1 = {0.f, 0.f, 0.f, 0.f};
        #pragma unroll
        for (int kt = 0; kt < 4; ++kt) {
            a0 = __builtin_amdgcn_mfma_f32_16x16x32_bf16(A[0][kt], Bf[kt], a0, 0, 0, 0);
            a1 = __builtin_amdgcn_mfma_f32_16x16x32_bf16(A[1][kt], Bf[kt], a1, 0, 0, 0);
        }
        f32x4 w0 = a0 * ey0;
        f32x4 w1 = a1 * ey1;

        if (tstep && (tstep & 3) == 0) {     // consume partials from tstep-1
            f32x4 ws = *(const f32x4*)wsumS;
            float S = (ws.x + ws.y) + (ws.z + ws.w);
            float rinv = __builtin_amdgcn_rcpf(S);
            c_acc += __logf(S);
            w0 *= rinv; w1 *= rinv;
        }
        if ((tstep & 3) == 3) {              // publish partial sums
            f32x4 sv = w0 + w1;
            float sp = (sv.x + sv.y) + (sv.z + sv.w);
            sp += __shfl_xor(sp, 16);
            sp += __shfl_xor(sp, 32);
            if (lane == 0) wsumS[w] = sp;
        }
        if (ci == 0) {                       // 8 x 8B writes per wave
            uint2 d0 = make_uint2(pkbf16(w0.x, w0.y), pkbf16(w0.z, w0.w));
            uint2 d1 = make_uint2(pkbf16(w1.x, w1.y), pkbf16(w1.z, w1.w));
            *(uint2*)&vS[cur ^ 1][32 * w + 4 * q]      = d0;
            *(uint2*)&vS[cur ^ 1][32 * w + 16 + 4 * q] = d1;
        }
        __syncthreads();
        cur ^= 1;
        ++tstep;
    };

    for (int c = 0; c < nch; ++c) {
        if (c + 1 < nch) {                   // prefetch next chunk
            stage(dir ? (L - 32 * (c + 2)) : (32 * (c + 1)), (c + 1) & 1);
            asm volatile("s_waitcnt vmcnt(4)" ::: "memory");   // chunk c done
        } else {
            asm volatile("s_waitcnt vmcnt(0)" ::: "memory");
        }
        __syncthreads();                     // all waves' DMA for chunk c visible
        float* bp = eybuf[c & 1];
        #pragma unroll
        for (int i = 0; i < 4; ++i) {        // pre-exp pass (4096 floats/256 thr)
            f32x4 v4 = *(const f32x4*)(bp + i * 1024 + tid * 4);
            v4.x = __expf(v4.x); v4.y = __expf(v4.y);
            v4.z = __expf(v4.z); v4.w = __expf(v4.w);
            *(f32x4*)(bp + i * 1024 + tid * 4) = v4;
        }
        __syncthreads();

        if (!dir) {                          // rows t = 32c + li, ascending
            const int ns = (H - 32 * c) < 32 ? (H - 32 * c) : 32;
            for (int li = 0; li < ns; ++li) step(bp + li * K_);
        } else {                             // rows t = base + li, descending
            if (c == 0) {                    // init z = ey_{L-1} (row 31)
                float a0 = bp[31 * K_ + 2 * lane];     // all waves write the
                float a1 = bp[31 * K_ + 2 * lane + 1]; // same words redundantly
                ((unsigned int*)&vS[0][0])[lane] = pkbf16(a0, a1);
                asm volatile("s_waitcnt lgkmcnt(0)" ::: "memory");
                __builtin_amdgcn_sched_barrier(0);
            }
            const int base = L - 32 * (c + 1);
            const int ls = (c == 0) ? 30 : 31;          // li=31 of c=0 was init
            int le = H - base; if (le < 0) le = 0;      // stop at t = H
            for (int li = ls; li >= le; --li) step(bp + li * K_);
        }
    }
    if (dir) step(nullptr);                  // final unscaled Texp^T application

    // ---- store end state (bf16 widened to f32) + log-scale ----
    if (tid < K_) {
        unsigned int hv = vS[cur][tid];
        vws[(size_t)bd * K_ + tid] = __builtin_bit_cast(float, hv << 16);
    }
    if (tid == 0) cws[bd] = c_acc;
}

// ---------------------------------------------------------------------------
// Combine: out[b] = c_f + c_b + log( v_H . w )
// ---------------------------------------------------------------------------
__global__ __launch_bounds__(128) void crf_comb_kernel(
    const float* __restrict__ vws,
    const float* __restrict__ cws,
    float* __restrict__ out)
{
    const int b   = blockIdx.x;
    const int tid = threadIdx.x;             // 0..127
    __shared__ float red2[2];

    float p = vws[(size_t)(2 * b) * K_ + tid] * vws[(size_t)(2 * b + 1) * K_ + tid];
    p += __shfl_xor(p, 1);  p += __shfl_xor(p, 2);
    p += __shfl_xor(p, 4);  p += __shfl_xor(p, 8);
    p += __shfl_xor(p, 16); p += __shfl_xor(p, 32);
    if ((tid & 63) == 0) red2[tid >> 6] = p;
    __syncthreads();
    if (tid == 0) out[b] = cws[2 * b] + cws[2 * b + 1] + __logf(red2[0] + red2[1]);
}

extern "C" void kernel_launch(void* const* d_in, const int* in_sizes, int n_in,
                              void* d_out, int out_size, void* d_ws, size_t ws_size,
                              hipStream_t stream) {
    const float* y     = (const float*)d_in[0];   // (B, T, K) fp32
    const float* mask  = (const float*)d_in[1];   // (B, T)    fp32 0/1
    const float* trans = (const float*)d_in[2];   // (K, K)    fp32
    float* out = (float*)d_out;                   // (B,)      fp32

    float* vws = (float*)d_ws;                              // 64 KB
    float* cws = (float*)((char*)d_ws + (size_t)B_ * 2 * K_ * sizeof(float));

    crf_chain_kernel<<<B_ * 2, 256, 0, stream>>>(y, mask, trans, vws, cws);
    crf_comb_kernel<<<B_, 128, 0, stream>>>(vws, cws, out);
}